// Round 3
// baseline (517.702 us; speedup 1.0000x reference)
//
#include <hip/hip_runtime.h>

// NonLocalAggregation on MI355X.
// Sizes fixed by setup_inputs(): b=32, f=64, h=w=32 (n=1024), out=64, k=8.
// Workspace layout (~9.2 MB):
//   xt  : [32][1024][64] fp32 transposed features
//   sq  : [32][1024]     fp32 squared norms
//   nbr : [32][1024][8]  int  neighbor indices
#define BATCH 32
#define FDIM  64
#define NPT   1024
#define KNN   8
#define OCH   64
#define INFF  3.402823466e+38f

// ---------------- kernel 1: transpose + squared norms ----------------
__global__ __launch_bounds__(256) void k_prep(const float* __restrict__ x,
                                              float* __restrict__ xt,
                                              float* __restrict__ sq) {
  __shared__ float t[64][65];  // [f][n_local], pad 65 -> conflict-free both ways
  const int bid = blockIdx.x;
  const int b   = bid >> 4;
  const int n0  = (bid & 15) << 6;
  const int tid = threadIdx.x;
  const int nl  = tid & 63;
  const int f0  = tid >> 6;
  const float* xb = x + (size_t)b * FDIM * NPT;
#pragma unroll
  for (int i = 0; i < 16; ++i) {
    const int f = f0 * 16 + i;
    t[f][nl] = xb[f * NPT + n0 + nl];          // coalesced over nl
  }
  __syncthreads();
  const int fl = tid & 63;
  const int g0 = tid >> 6;
  float* xtb = xt + ((size_t)b * NPT + n0) * FDIM;
#pragma unroll
  for (int i = 0; i < 16; ++i) {
    const int nn = g0 * 16 + i;
    xtb[nn * FDIM + fl] = t[fl][nn];           // coalesced over fl
  }
  if (tid < 64) {
    float s = 0.f;
#pragma unroll
    for (int f = 0; f < 64; ++f) s = fmaf(t[f][tid], t[f][tid], s);
    sq[b * NPT + n0 + tid] = s;
  }
}

// ---------------- kernel 2: pairwise distances + top-8 ----------------
// Block: 256 threads = 32 rows x 8 column-chunks. 1024 blocks (4/CU exactly).
// Score = sq[m] - 2*dot(p, x_m)  (row-constant sq[r] dropped: ordering invariant).
// Top-8 kept in NAMED scalar registers (d0..d7 ascending), branchless sorted
// insert, always executed: no divergence, no scratch (round-1 lesson:
// 505 MB/dispatch of scratch writes from array-based evict-max).
__global__ __launch_bounds__(256, 4) void k_knn(const float* __restrict__ xt,
                                                const float* __restrict__ sq,
                                                int* __restrict__ nbr) {
  __shared__ float tile[64 * 64];   // 64 columns x 64 features, linear
  __shared__ float sqt[64];
  __shared__ float cand_d[32][65];  // 8 sorted 8-lists per row; pad 65
  __shared__ int   cand_i[32][65];

  const int bid = blockIdx.x;
  const int b   = bid >> 5;
  const int r0  = (bid & 31) << 5;
  const int tid = threadIdx.x;
  const int l   = tid & 31;   // row within block
  const int w   = tid >> 5;   // column chunk 0..7

  // own row features -> 64 VGPRs
  float4 pr[16];
  {
    const float4* prow = (const float4*)(xt + ((size_t)b * NPT + r0 + l) * FDIM);
#pragma unroll
    for (int q = 0; q < 16; ++q) pr[q] = prow[q];
  }

  // ascending sorted top-8: d0 <= d1 <= ... <= d7 (worst)
  float d0=INFF,d1=INFF,d2=INFF,d3=INFF,d4=INFF,d5=INFF,d6=INFF,d7=INFF;
  int   i0=0,i1=0,i2=0,i3=0,i4=0,i5=0,i6=0,i7=0;

  // branchless sorted insert; strict < keeps earliest-seen (lowest idx) on ties
  auto ins = [&](float k, int idx) {
    const bool c0 = k < d0, c1 = k < d1, c2 = k < d2, c3 = k < d3,
               c4 = k < d4, c5 = k < d5, c6 = k < d6, c7 = k < d7;
    d7 = c6 ? d6 : (c7 ? k : d7);  i7 = c6 ? i6 : (c7 ? idx : i7);
    d6 = c5 ? d5 : (c6 ? k : d6);  i6 = c5 ? i5 : (c6 ? idx : i6);
    d5 = c4 ? d4 : (c5 ? k : d5);  i5 = c4 ? i4 : (c5 ? idx : i5);
    d4 = c3 ? d3 : (c4 ? k : d4);  i4 = c3 ? i3 : (c4 ? idx : i4);
    d3 = c2 ? d2 : (c3 ? k : d3);  i3 = c2 ? i2 : (c3 ? idx : i3);
    d2 = c1 ? d1 : (c2 ? k : d2);  i2 = c1 ? i1 : (c2 ? idx : i2);
    d1 = c0 ? d0 : (c1 ? k : d1);  i1 = c0 ? i0 : (c1 ? idx : i1);
    d0 = c0 ? k  : d0;             i0 = c0 ? idx : i0;
  };

  for (int ct = 0; ct < 16; ++ct) {
    const int cbase = ct * 64;
    {  // stage 16 KB column tile (contiguous in xt) + norms
      const float4* src = (const float4*)(xt + ((size_t)b * NPT + cbase) * FDIM);
      float4* dst = (float4*)tile;
#pragma unroll
      for (int q = 0; q < 4; ++q) dst[tid + q * 256] = src[tid + q * 256];
      if (tid < 64) sqt[tid] = sq[b * NPT + cbase + tid];
    }
    __syncthreads();

#pragma unroll
    for (int mm0 = 0; mm0 < 8; mm0 += 4) {
      const int mc = 8 * w + mm0;
      const float4* t0 = (const float4*)(tile + (mc + 0) * 64);
      const float4* t1 = (const float4*)(tile + (mc + 1) * 64);
      const float4* t2 = (const float4*)(tile + (mc + 2) * 64);
      const float4* t3 = (const float4*)(tile + (mc + 3) * 64);
      float a0 = 0.f, a1 = 0.f, a2 = 0.f, a3 = 0.f;
#pragma unroll
      for (int q = 0; q < 16; ++q) {
        const float4 pv = pr[q];
        const float4 v0 = t0[q], v1 = t1[q], v2 = t2[q], v3 = t3[q];
        a0 = fmaf(pv.x, v0.x, fmaf(pv.y, v0.y, fmaf(pv.z, v0.z, fmaf(pv.w, v0.w, a0))));
        a1 = fmaf(pv.x, v1.x, fmaf(pv.y, v1.y, fmaf(pv.z, v1.z, fmaf(pv.w, v1.w, a1))));
        a2 = fmaf(pv.x, v2.x, fmaf(pv.y, v2.y, fmaf(pv.z, v2.z, fmaf(pv.w, v2.w, a2))));
        a3 = fmaf(pv.x, v3.x, fmaf(pv.y, v3.y, fmaf(pv.z, v3.z, fmaf(pv.w, v3.w, a3))));
      }
      const int mg = cbase + mc;
      ins(fmaf(-2.f, a0, sqt[mc + 0]), mg + 0);
      ins(fmaf(-2.f, a1, sqt[mc + 1]), mg + 1);
      ins(fmaf(-2.f, a2, sqt[mc + 2]), mg + 2);
      ins(fmaf(-2.f, a3, sqt[mc + 3]), mg + 3);
    }
    __syncthreads();
  }

  // publish sorted per-chunk top-8
  {
    float* cd = &cand_d[l][w * 8];
    int*   ci = &cand_i[l][w * 8];
    cd[0]=d0; cd[1]=d1; cd[2]=d2; cd[3]=d3; cd[4]=d4; cd[5]=d5; cd[6]=d6; cd[7]=d7;
    ci[0]=i0; ci[1]=i1; ci[2]=i2; ci[3]=i3; ci[4]=i4; ci[5]=i5; ci[6]=i6; ci[7]=i7;
  }
  __syncthreads();

  // 8-way sorted-list head merge per row (named heads: rule #20, no scratch)
  if (tid < 32) {
    const int r = tid;
    int h0=0,h1=0,h2=0,h3=0,h4=0,h5=0,h6=0,h7=0;
    int* outp = nbr + ((size_t)b * NPT + r0 + r) * KNN;
#pragma unroll 1
    for (int s = 0; s < 8; ++s) {
      float bd = cand_d[r][h0]; int bi = cand_i[r][h0]; int bw = 0;
      { const float cd_=cand_d[r][ 8+h1]; const int ci_=cand_i[r][ 8+h1];
        if (cd_<bd || (cd_==bd && ci_<bi)) { bd=cd_; bi=ci_; bw=1; } }
      { const float cd_=cand_d[r][16+h2]; const int ci_=cand_i[r][16+h2];
        if (cd_<bd || (cd_==bd && ci_<bi)) { bd=cd_; bi=ci_; bw=2; } }
      { const float cd_=cand_d[r][24+h3]; const int ci_=cand_i[r][24+h3];
        if (cd_<bd || (cd_==bd && ci_<bi)) { bd=cd_; bi=ci_; bw=3; } }
      { const float cd_=cand_d[r][32+h4]; const int ci_=cand_i[r][32+h4];
        if (cd_<bd || (cd_==bd && ci_<bi)) { bd=cd_; bi=ci_; bw=4; } }
      { const float cd_=cand_d[r][40+h5]; const int ci_=cand_i[r][40+h5];
        if (cd_<bd || (cd_==bd && ci_<bi)) { bd=cd_; bi=ci_; bw=5; } }
      { const float cd_=cand_d[r][48+h6]; const int ci_=cand_i[r][48+h6];
        if (cd_<bd || (cd_==bd && ci_<bi)) { bd=cd_; bi=ci_; bw=6; } }
      { const float cd_=cand_d[r][56+h7]; const int ci_=cand_i[r][56+h7];
        if (cd_<bd || (cd_==bd && ci_<bi)) { bd=cd_; bi=ci_; bw=7; } }
      outp[s] = bi;
      h0 += (bw==0); h1 += (bw==1); h2 += (bw==2); h3 += (bw==3);
      h4 += (bw==4); h5 += (bw==5); h6 += (bw==6); h7 += (bw==7);
    }
  }
}

// ---------------- kernel 3: gather + fused dual matvec ----------------
// out[b,o,n] = Wd·(mean8(nbr)-xf) + Ws·xf + (bd+bs+bias)
__global__ __launch_bounds__(256, 2) void k_out(const float* __restrict__ xt,
                                                const int* __restrict__ nbr,
                                                const float* __restrict__ Wd,
                                                const float* __restrict__ bdv,
                                                const float* __restrict__ Ws,
                                                const float* __restrict__ bsv,
                                                const float* __restrict__ bias,
                                                float* __restrict__ out) {
  __shared__ float wtd[64][68];  // W^T [f][o]
  __shared__ float wts[64][68];
  __shared__ float mdt[64][65];  // meanDiff^T [f][r]
  __shared__ float xrt[64][65];  // xf^T       [f][r]
  __shared__ float cb[64];

  const int bid = blockIdx.x;
  const int b   = bid >> 4;
  const int r0  = (bid & 15) << 6;
  const int tid = threadIdx.x;

  {  // stage weights transposed (coalesced global reads over f)
    const int fl = tid & 63, og = tid >> 6;
#pragma unroll
    for (int i = 0; i < 16; ++i) {
      const int o = og * 16 + i;
      wtd[fl][o] = Wd[o * 64 + fl];
      wts[fl][o] = Ws[o * 64 + fl];
    }
    if (tid < 64) cb[tid] = bdv[tid] + bsv[tid] + bias[tid];
  }

  {  // gather: thread (r, c) owns f-segment [16c,16c+16) of row r0+r
    const int r = tid & 63, c = tid >> 6;
    const int row = r0 + r;
    const int* np = nbr + ((size_t)b * NPT + row) * KNN;
    float s[16];
#pragma unroll
    for (int q = 0; q < 16; ++q) s[q] = 0.f;
    for (int s8 = 0; s8 < 8; ++s8) {
      const int j = np[s8];
      const float4* nv = (const float4*)(xt + ((size_t)b * NPT + j) * FDIM + c * 16);
#pragma unroll
      for (int q = 0; q < 4; ++q) {
        const float4 v = nv[q];
        s[q * 4 + 0] += v.x; s[q * 4 + 1] += v.y;
        s[q * 4 + 2] += v.z; s[q * 4 + 3] += v.w;
      }
    }
    const float4* xv4 = (const float4*)(xt + ((size_t)b * NPT + row) * FDIM + c * 16);
#pragma unroll
    for (int q = 0; q < 4; ++q) {
      const float4 xv = xv4[q];
      const int f = c * 16 + q * 4;
      mdt[f + 0][r] = fmaf(s[q * 4 + 0], 0.125f, -xv.x);
      mdt[f + 1][r] = fmaf(s[q * 4 + 1], 0.125f, -xv.y);
      mdt[f + 2][r] = fmaf(s[q * 4 + 2], 0.125f, -xv.z);
      mdt[f + 3][r] = fmaf(s[q * 4 + 3], 0.125f, -xv.w);
      xrt[f + 0][r] = xv.x;
      xrt[f + 1][r] = xv.y;
      xrt[f + 2][r] = xv.z;
      xrt[f + 3][r] = xv.w;
    }
  }
  __syncthreads();

  {  // matvec: thread (r, oc) computes 16 outputs of row r0+r
    const int r = tid & 63, oc = tid >> 6;
    float acc[16];
#pragma unroll
    for (int j = 0; j < 16; ++j) acc[j] = cb[oc * 16 + j];
#pragma unroll 4
    for (int f = 0; f < 64; ++f) {
      const float mv = mdt[f][r];
      const float xv = xrt[f][r];
      const float4* w4 = (const float4*)(&wtd[f][oc * 16]);  // broadcast b128
      const float4* v4 = (const float4*)(&wts[f][oc * 16]);
#pragma unroll
      for (int q = 0; q < 4; ++q) {
        const float4 a = w4[q], bb = v4[q];
        acc[q * 4 + 0] = fmaf(a.x, mv, fmaf(bb.x, xv, acc[q * 4 + 0]));
        acc[q * 4 + 1] = fmaf(a.y, mv, fmaf(bb.y, xv, acc[q * 4 + 1]));
        acc[q * 4 + 2] = fmaf(a.z, mv, fmaf(bb.z, xv, acc[q * 4 + 2]));
        acc[q * 4 + 3] = fmaf(a.w, mv, fmaf(bb.w, xv, acc[q * 4 + 3]));
      }
    }
    const int row = r0 + r;
    float* op = out + (size_t)b * OCH * NPT + row;
#pragma unroll
    for (int j = 0; j < 16; ++j) op[(oc * 16 + j) * NPT] = acc[j];  // coalesced over r
  }
}

extern "C" void kernel_launch(void* const* d_in, const int* in_sizes, int n_in,
                              void* d_out, int out_size, void* d_ws, size_t ws_size,
                              hipStream_t stream) {
  const float* x    = (const float*)d_in[0];
  const float* Wd   = (const float*)d_in[1];
  const float* bd   = (const float*)d_in[2];
  const float* Ws   = (const float*)d_in[3];
  const float* bs   = (const float*)d_in[4];
  const float* bias = (const float*)d_in[5];
  // d_in[6] is k == 8, hardcoded (register top-k requires compile-time k)
  float* out = (float*)d_out;

  float* xt  = (float*)d_ws;                          // 2,097,152 floats
  float* sqw = xt + (size_t)BATCH * NPT * FDIM;       //    32,768 floats
  int*   nbr = (int*)(sqw + (size_t)BATCH * NPT);     //   262,144 ints

  k_prep<<<dim3(BATCH * 16), dim3(256), 0, stream>>>(x, xt, sqw);
  k_knn <<<dim3(BATCH * 32), dim3(256), 0, stream>>>(xt, sqw, nbr);
  k_out <<<dim3(BATCH * 16), dim3(256), 0, stream>>>(xt, nbr, Wd, bd, Ws, bs, bias, out);
}

// Round 5
// 241.141 us; speedup vs baseline: 2.1469x; 2.1469x over previous
//
#include <hip/hip_runtime.h>

// NonLocalAggregation on MI355X.
// Sizes fixed by setup_inputs(): b=32, f=64, h=w=32 (n=1024), out=64, k=8.
// Workspace layout (~9.2 MB):
//   xt  : [32][1024][64] fp32 transposed features
//   sq  : [32][1024]     fp32 squared norms
//   nbr : [32][1024][8]  int  neighbor indices
#define BATCH 32
#define FDIM  64
#define NPT   1024
#define KNN   8
#define OCH   64
#define INFF  3.402823466e+38f

// ---------------- kernel 1: transpose + squared norms ----------------
__global__ __launch_bounds__(256) void k_prep(const float* __restrict__ x,
                                              float* __restrict__ xt,
                                              float* __restrict__ sq) {
  __shared__ float t[64][65];  // [f][n_local], pad 65 -> conflict-free both ways
  const int bid = blockIdx.x;
  const int b   = bid >> 4;
  const int n0  = (bid & 15) << 6;
  const int tid = threadIdx.x;
  const int nl  = tid & 63;
  const int f0  = tid >> 6;
  const float* xb = x + (size_t)b * FDIM * NPT;
#pragma unroll
  for (int i = 0; i < 16; ++i) {
    const int f = f0 * 16 + i;
    t[f][nl] = xb[f * NPT + n0 + nl];          // coalesced over nl
  }
  __syncthreads();
  const int fl = tid & 63;
  const int g0 = tid >> 6;
  float* xtb = xt + ((size_t)b * NPT + n0) * FDIM;
#pragma unroll
  for (int i = 0; i < 16; ++i) {
    const int nn = g0 * 16 + i;
    xtb[nn * FDIM + fl] = t[fl][nn];           // coalesced over fl
  }
  if (tid < 64) {
    float s = 0.f;
#pragma unroll
    for (int f = 0; f < 64; ++f) s = fmaf(t[f][tid], t[f][tid], s);
    sq[b * NPT + n0 + tid] = s;
  }
}

// ---------------- kernel 2: pairwise distances + top-8 ----------------
// Block: 256 threads = 32 rows x 8 column-chunks. 1024 blocks (4/CU).
// Score = sq[m] - 2*dot(p, x_m)  (row-constant sq[r] dropped: ordering invariant).
// Top-8 in NAMED scalar registers (branchless sorted insert, no divergence,
// no scratch). Round-3 lesson: __launch_bounds__(256,4) made the allocator
// target 64 VGPRs and spill pr[16] (FETCH 974 MB). (256,2) gives ~128 VGPRs
// (round-1 evidence) which fits pr[16]+state with no spills.
__global__ __launch_bounds__(256, 2) void k_knn(const float* __restrict__ xt,
                                                const float* __restrict__ sq,
                                                int* __restrict__ nbr) {
  __shared__ float tile[64 * 64];   // 64 columns x 64 features, linear
  __shared__ float sqt[64];
  __shared__ float cand_d[32][65];  // 8 sorted 8-lists per row; pad 65
  __shared__ int   cand_i[32][65];

  const int bid = blockIdx.x;
  const int b   = bid >> 5;
  const int r0  = (bid & 31) << 5;
  const int tid = threadIdx.x;
  const int l   = tid & 31;   // row within block
  const int w   = tid >> 5;   // column chunk 0..7

  // own row features -> 64 VGPRs
  float4 pr[16];
  {
    const float4* prow = (const float4*)(xt + ((size_t)b * NPT + r0 + l) * FDIM);
#pragma unroll
    for (int q = 0; q < 16; ++q) pr[q] = prow[q];
  }

  // ascending sorted top-8: d0 <= d1 <= ... <= d7 (worst)
  float d0=INFF,d1=INFF,d2=INFF,d3=INFF,d4=INFF,d5=INFF,d6=INFF,d7=INFF;
  int   i0=0,i1=0,i2=0,i3=0,i4=0,i5=0,i6=0,i7=0;

  // branchless sorted insert; strict < keeps earliest-seen (lowest idx) on ties
  auto ins = [&](float k, int idx) {
    const bool c0 = k < d0, c1 = k < d1, c2 = k < d2, c3 = k < d3,
               c4 = k < d4, c5 = k < d5, c6 = k < d6, c7 = k < d7;
    d7 = c6 ? d6 : (c7 ? k : d7);  i7 = c6 ? i6 : (c7 ? idx : i7);
    d6 = c5 ? d5 : (c6 ? k : d6);  i6 = c5 ? i5 : (c6 ? idx : i6);
    d5 = c4 ? d4 : (c5 ? k : d5);  i5 = c4 ? i4 : (c5 ? idx : i5);
    d4 = c3 ? d3 : (c4 ? k : d4);  i4 = c3 ? i3 : (c4 ? idx : i4);
    d3 = c2 ? d2 : (c3 ? k : d3);  i3 = c2 ? i2 : (c3 ? idx : i3);
    d2 = c1 ? d1 : (c2 ? k : d2);  i2 = c1 ? i1 : (c2 ? idx : i2);
    d1 = c0 ? d0 : (c1 ? k : d1);  i1 = c0 ? i0 : (c1 ? idx : i1);
    d0 = c0 ? k  : d0;             i0 = c0 ? idx : i0;
  };

  for (int ct = 0; ct < 16; ++ct) {
    const int cbase = ct * 64;
    {  // stage 16 KB column tile (contiguous in xt) + norms
      const float4* src = (const float4*)(xt + ((size_t)b * NPT + cbase) * FDIM);
      float4* dst = (float4*)tile;
#pragma unroll
      for (int q = 0; q < 4; ++q) dst[tid + q * 256] = src[tid + q * 256];
      if (tid < 64) sqt[tid] = sq[b * NPT + cbase + tid];
    }
    __syncthreads();

#pragma unroll
    for (int mm0 = 0; mm0 < 8; mm0 += 4) {
      const int mc = 8 * w + mm0;
      const float4* t0 = (const float4*)(tile + (mc + 0) * 64);
      const float4* t1 = (const float4*)(tile + (mc + 1) * 64);
      const float4* t2 = (const float4*)(tile + (mc + 2) * 64);
      const float4* t3 = (const float4*)(tile + (mc + 3) * 64);
      float a0 = 0.f, a1 = 0.f, a2 = 0.f, a3 = 0.f;
#pragma unroll
      for (int q = 0; q < 16; ++q) {
        const float4 pv = pr[q];
        const float4 v0 = t0[q], v1 = t1[q], v2 = t2[q], v3 = t3[q];
        a0 = fmaf(pv.x, v0.x, fmaf(pv.y, v0.y, fmaf(pv.z, v0.z, fmaf(pv.w, v0.w, a0))));
        a1 = fmaf(pv.x, v1.x, fmaf(pv.y, v1.y, fmaf(pv.z, v1.z, fmaf(pv.w, v1.w, a1))));
        a2 = fmaf(pv.x, v2.x, fmaf(pv.y, v2.y, fmaf(pv.z, v2.z, fmaf(pv.w, v2.w, a2))));
        a3 = fmaf(pv.x, v3.x, fmaf(pv.y, v3.y, fmaf(pv.z, v3.z, fmaf(pv.w, v3.w, a3))));
      }
      const int mg = cbase + mc;
      ins(fmaf(-2.f, a0, sqt[mc + 0]), mg + 0);
      ins(fmaf(-2.f, a1, sqt[mc + 1]), mg + 1);
      ins(fmaf(-2.f, a2, sqt[mc + 2]), mg + 2);
      ins(fmaf(-2.f, a3, sqt[mc + 3]), mg + 3);
    }
    __syncthreads();
  }

  // publish sorted per-chunk top-8
  {
    float* cd = &cand_d[l][w * 8];
    int*   ci = &cand_i[l][w * 8];
    cd[0]=d0; cd[1]=d1; cd[2]=d2; cd[3]=d3; cd[4]=d4; cd[5]=d5; cd[6]=d6; cd[7]=d7;
    ci[0]=i0; ci[1]=i1; ci[2]=i2; ci[3]=i3; ci[4]=i4; ci[5]=i5; ci[6]=i6; ci[7]=i7;
  }
  __syncthreads();

  // 8-way sorted-list head merge per row (named heads: rule #20, no scratch)
  if (tid < 32) {
    const int r = tid;
    int h0=0,h1=0,h2=0,h3=0,h4=0,h5=0,h6=0,h7=0;
    int* outp = nbr + ((size_t)b * NPT + r0 + r) * KNN;
#pragma unroll 1
    for (int s = 0; s < 8; ++s) {
      float bd = cand_d[r][h0]; int bi = cand_i[r][h0]; int bw = 0;
      { const float cd_=cand_d[r][ 8+h1]; const int ci_=cand_i[r][ 8+h1];
        if (cd_<bd || (cd_==bd && ci_<bi)) { bd=cd_; bi=ci_; bw=1; } }
      { const float cd_=cand_d[r][16+h2]; const int ci_=cand_i[r][16+h2];
        if (cd_<bd || (cd_==bd && ci_<bi)) { bd=cd_; bi=ci_; bw=2; } }
      { const float cd_=cand_d[r][24+h3]; const int ci_=cand_i[r][24+h3];
        if (cd_<bd || (cd_==bd && ci_<bi)) { bd=cd_; bi=ci_; bw=3; } }
      { const float cd_=cand_d[r][32+h4]; const int ci_=cand_i[r][32+h4];
        if (cd_<bd || (cd_==bd && ci_<bi)) { bd=cd_; bi=ci_; bw=4; } }
      { const float cd_=cand_d[r][40+h5]; const int ci_=cand_i[r][40+h5];
        if (cd_<bd || (cd_==bd && ci_<bi)) { bd=cd_; bi=ci_; bw=5; } }
      { const float cd_=cand_d[r][48+h6]; const int ci_=cand_i[r][48+h6];
        if (cd_<bd || (cd_==bd && ci_<bi)) { bd=cd_; bi=ci_; bw=6; } }
      { const float cd_=cand_d[r][56+h7]; const int ci_=cand_i[r][56+h7];
        if (cd_<bd || (cd_==bd && ci_<bi)) { bd=cd_; bi=ci_; bw=7; } }
      outp[s] = bi;
      h0 += (bw==0); h1 += (bw==1); h2 += (bw==2); h3 += (bw==3);
      h4 += (bw==4); h5 += (bw==5); h6 += (bw==6); h7 += (bw==7);
    }
  }
}

// ---------------- kernel 3: gather + fused dual matvec ----------------
// out[b,o,n] = Wd·(mean8(nbr)-xf) + Ws·xf + (bd+bs+bias)
__global__ __launch_bounds__(256, 2) void k_out(const float* __restrict__ xt,
                                                const int* __restrict__ nbr,
                                                const float* __restrict__ Wd,
                                                const float* __restrict__ bdv,
                                                const float* __restrict__ Ws,
                                                const float* __restrict__ bsv,
                                                const float* __restrict__ bias,
                                                float* __restrict__ out) {
  __shared__ float wtd[64][68];  // W^T [f][o]
  __shared__ float wts[64][68];
  __shared__ float mdt[64][65];  // meanDiff^T [f][r]
  __shared__ float xrt[64][65];  // xf^T       [f][r]
  __shared__ float cb[64];

  const int bid = blockIdx.x;
  const int b   = bid >> 4;
  const int r0  = (bid & 15) << 6;
  const int tid = threadIdx.x;

  {  // stage weights transposed (coalesced global reads over f)
    const int fl = tid & 63, og = tid >> 6;
#pragma unroll
    for (int i = 0; i < 16; ++i) {
      const int o = og * 16 + i;
      wtd[fl][o] = Wd[o * 64 + fl];
      wts[fl][o] = Ws[o * 64 + fl];
    }
    if (tid < 64) cb[tid] = bdv[tid] + bsv[tid] + bias[tid];
  }

  {  // gather: thread (r, c) owns f-segment [16c,16c+16) of row r0+r
    const int r = tid & 63, c = tid >> 6;
    const int row = r0 + r;
    const int* np = nbr + ((size_t)b * NPT + row) * KNN;
    float s[16];
#pragma unroll
    for (int q = 0; q < 16; ++q) s[q] = 0.f;
    for (int s8 = 0; s8 < 8; ++s8) {
      const int j = np[s8];
      const float4* nv = (const float4*)(xt + ((size_t)b * NPT + j) * FDIM + c * 16);
#pragma unroll
      for (int q = 0; q < 4; ++q) {
        const float4 v = nv[q];
        s[q * 4 + 0] += v.x; s[q * 4 + 1] += v.y;
        s[q * 4 + 2] += v.z; s[q * 4 + 3] += v.w;
      }
    }
    const float4* xv4 = (const float4*)(xt + ((size_t)b * NPT + row) * FDIM + c * 16);
#pragma unroll
    for (int q = 0; q < 4; ++q) {
      const float4 xv = xv4[q];
      const int f = c * 16 + q * 4;
      mdt[f + 0][r] = fmaf(s[q * 4 + 0], 0.125f, -xv.x);
      mdt[f + 1][r] = fmaf(s[q * 4 + 1], 0.125f, -xv.y);
      mdt[f + 2][r] = fmaf(s[q * 4 + 2], 0.125f, -xv.z);
      mdt[f + 3][r] = fmaf(s[q * 4 + 3], 0.125f, -xv.w);
      xrt[f + 0][r] = xv.x;
      xrt[f + 1][r] = xv.y;
      xrt[f + 2][r] = xv.z;
      xrt[f + 3][r] = xv.w;
    }
  }
  __syncthreads();

  {  // matvec: thread (r, oc) computes 16 outputs of row r0+r
    const int r = tid & 63, oc = tid >> 6;
    float acc[16];
#pragma unroll
    for (int j = 0; j < 16; ++j) acc[j] = cb[oc * 16 + j];
#pragma unroll 4
    for (int f = 0; f < 64; ++f) {
      const float mv = mdt[f][r];
      const float xv = xrt[f][r];
      const float4* w4 = (const float4*)(&wtd[f][oc * 16]);  // broadcast b128
      const float4* v4 = (const float4*)(&wts[f][oc * 16]);
#pragma unroll
      for (int q = 0; q < 4; ++q) {
        const float4 a = w4[q], bb = v4[q];
        acc[q * 4 + 0] = fmaf(a.x, mv, fmaf(bb.x, xv, acc[q * 4 + 0]));
        acc[q * 4 + 1] = fmaf(a.y, mv, fmaf(bb.y, xv, acc[q * 4 + 1]));
        acc[q * 4 + 2] = fmaf(a.z, mv, fmaf(bb.z, xv, acc[q * 4 + 2]));
        acc[q * 4 + 3] = fmaf(a.w, mv, fmaf(bb.w, xv, acc[q * 4 + 3]));
      }
    }
    const int row = r0 + r;
    float* op = out + (size_t)b * OCH * NPT + row;
#pragma unroll
    for (int j = 0; j < 16; ++j) op[(oc * 16 + j) * NPT] = acc[j];  // coalesced over r
  }
}

extern "C" void kernel_launch(void* const* d_in, const int* in_sizes, int n_in,
                              void* d_out, int out_size, void* d_ws, size_t ws_size,
                              hipStream_t stream) {
  const float* x    = (const float*)d_in[0];
  const float* Wd   = (const float*)d_in[1];
  const float* bd   = (const float*)d_in[2];
  const float* Ws   = (const float*)d_in[3];
  const float* bs   = (const float*)d_in[4];
  const float* bias = (const float*)d_in[5];
  // d_in[6] is k == 8, hardcoded (register top-k requires compile-time k)
  float* out = (float*)d_out;

  float* xt  = (float*)d_ws;                          // 2,097,152 floats
  float* sqw = xt + (size_t)BATCH * NPT * FDIM;       //    32,768 floats
  int*   nbr = (int*)(sqw + (size_t)BATCH * NPT);     //   262,144 ints

  k_prep<<<dim3(BATCH * 16), dim3(256), 0, stream>>>(x, xt, sqw);
  k_knn <<<dim3(BATCH * 32), dim3(256), 0, stream>>>(xt, sqw, nbr);
  k_out <<<dim3(BATCH * 16), dim3(256), 0, stream>>>(xt, nbr, Wd, bd, Ws, bs, bias, out);
}

// Round 7
// 193.817 us; speedup vs baseline: 2.6711x; 1.2442x over previous
//
#include <hip/hip_runtime.h>

// NonLocalAggregation on MI355X.
// Sizes fixed by setup_inputs(): b=32, f=64, h=w=32 (n=1024), out=64, k=8.
// Workspace: xt [32][1024][64] fp32, sq [32][1024] fp32, nbr [32][1024][8] int.
#define BATCH 32
#define FDIM  64
#define NPT   1024
#define KNN   8
#define OCH   64
#define INFF  3.402823466e+38f

// ---------------- kernel 1: transpose + squared norms ----------------
__global__ __launch_bounds__(256) void k_prep(const float* __restrict__ x,
                                              float* __restrict__ xt,
                                              float* __restrict__ sq) {
  __shared__ float t[64][65];
  const int bid = blockIdx.x;
  const int b   = bid >> 4;
  const int n0  = (bid & 15) << 6;
  const int tid = threadIdx.x;
  const int nl  = tid & 63;
  const int f0  = tid >> 6;
  const float* xb = x + (size_t)b * FDIM * NPT;
#pragma unroll
  for (int i = 0; i < 16; ++i) {
    const int f = f0 * 16 + i;
    t[f][nl] = xb[f * NPT + n0 + nl];
  }
  __syncthreads();
  const int fl = tid & 63;
  const int g0 = tid >> 6;
  float* xtb = xt + ((size_t)b * NPT + n0) * FDIM;
#pragma unroll
  for (int i = 0; i < 16; ++i) {
    const int nn = g0 * 16 + i;
    xtb[nn * FDIM + fl] = t[fl][nn];
  }
  if (tid < 64) {
    float s = 0.f;
#pragma unroll
    for (int f = 0; f < 64; ++f) s = fmaf(t[f][tid], t[f][tid], s);
    sq[b * NPT + n0 + tid] = s;
  }
}

// ---------------- kernel 2: pairwise distances + top-8 (v3) ----------------
// Register-tiled: block = 64 rows x 1024 cols, 256 thr, per-thread 8x4 subtile.
// Round-5 lesson: 16 ds_read_b128 per pair made the LDS pipe the bottleneck
// (109 us of LDS time vs 44 us VALU). Now 3 b128 feed 32 fmaf per f-step.
// Reads x directly ([b][f][n] is the layout the dot wants). Scores round-trip
// through LDS (reusing colF space) with a 2-level swizzle that is
// conflict-free on BOTH write (lanes vary rg,cg) and read (lanes vary row).
__global__ __launch_bounds__(256, 2) void k_knn(const float* __restrict__ x,
                                                const float* __restrict__ sq,
                                                int* __restrict__ nbr) {
  __shared__ float rowF[64][68];     // [f][row-local], stride 68 (16B-aligned)
  __shared__ float colB[64 * 132];   // dot: [f][col] stride 132; then scores [64][128] swizzled
  __shared__ float cand_d[64][33];   // 4 sorted 8-lists per row
  __shared__ int   cand_i[64][33];

  const int bid = blockIdx.x;
  const int b   = bid >> 4;          // 32 batches x 16 row-tiles = 512 blocks
  const int r0  = (bid & 15) << 6;
  const int tid = threadIdx.x;
  const int rg  = tid >> 5;          // row group 0..7 (8 rows each)
  const int cg  = tid & 31;          // col group 0..31 (4 cols each)

  const float* xb = x + (size_t)b * FDIM * NPT;

  // stage rowF once per block: rows r0..r0+63, all 64 features (coalesced)
#pragma unroll
  for (int k = 0; k < 4; ++k) {
    const int qid = tid + k * 256;            // 0..1023
    const int f = qid >> 4, rq = qid & 15;
    *(float4*)(&rowF[f][rq * 4]) = *(const float4*)(xb + f * NPT + r0 + rq * 4);
  }

  // selection state: ascending sorted top-8 in NAMED regs (round-5 proven)
  float d0=INFF,d1=INFF,d2=INFF,d3=INFF,d4=INFF,d5=INFF,d6=INFF,d7=INFF;
  int   i0=0,i1=0,i2=0,i3=0,i4=0,i5=0,i6=0,i7=0;
  auto ins = [&](float k, int idx) {
    const bool c0 = k < d0, c1 = k < d1, c2 = k < d2, c3 = k < d3,
               c4 = k < d4, c5 = k < d5, c6 = k < d6, c7 = k < d7;
    d7 = c6 ? d6 : (c7 ? k : d7);  i7 = c6 ? i6 : (c7 ? idx : i7);
    d6 = c5 ? d5 : (c6 ? k : d6);  i6 = c5 ? i5 : (c6 ? idx : i6);
    d5 = c4 ? d4 : (c5 ? k : d5);  i5 = c4 ? i4 : (c5 ? idx : i5);
    d4 = c3 ? d3 : (c4 ? k : d4);  i4 = c3 ? i3 : (c4 ? idx : i4);
    d3 = c2 ? d2 : (c3 ? k : d3);  i3 = c2 ? i2 : (c3 ? idx : i3);
    d2 = c1 ? d1 : (c2 ? k : d2);  i2 = c1 ? i1 : (c2 ? idx : i2);
    d1 = c0 ? d0 : (c1 ? k : d1);  i1 = c0 ? i0 : (c1 ? idx : i1);
    d0 = c0 ? k  : d0;             i0 = c0 ? idx : i0;
  };

  const int selrow = tid & 63;  // selection mapping: 64 rows x 4 col-segments
  const int selseg = tid >> 6;
  const int srb5 = selrow & 31;
  const int sq3  = (selrow >> 3) & 3;

  for (int ct = 0; ct < 8; ++ct) {
    const int c0 = ct * 128;
    __syncthreads();  // prev selection reads done -> colB writable (covers rowF stage on iter 0)
    // stage colF[f][c] for 128 cols (coalesced over n)
#pragma unroll
    for (int k = 0; k < 8; ++k) {
      const int qid = tid + k * 256;          // 0..2047
      const int f = qid >> 5, cq = qid & 31;
      *(float4*)(&colB[f * 132 + cq * 4]) = *(const float4*)(xb + f * NPT + c0 + cq * 4);
    }
    __syncthreads();

    float acc[8][4];
#pragma unroll
    for (int i = 0; i < 8; ++i)
#pragma unroll
      for (int c = 0; c < 4; ++c) acc[i][c] = 0.f;

#pragma unroll 4
    for (int f = 0; f < 64; ++f) {
      const float4 ra = *(const float4*)(&rowF[f][rg * 8]);      // broadcast (2 addrs/wave)
      const float4 rb = *(const float4*)(&rowF[f][rg * 8 + 4]);
      const float4 cv = *(const float4*)(&colB[f * 132 + cg * 4]);
      const float rv[8]  = {ra.x, ra.y, ra.z, ra.w, rb.x, rb.y, rb.z, rb.w};
      const float cvv[4] = {cv.x, cv.y, cv.z, cv.w};
#pragma unroll
      for (int i = 0; i < 8; ++i)
#pragma unroll
        for (int c = 0; c < 4; ++c)
          acc[i][c] = fmaf(rv[i], cvv[c], acc[i][c]);
    }

    // score = sq[col] - 2*dot  (row-constant sq[row] dropped: ordering invariant)
    const float4 sqv = *(const float4*)(sq + (size_t)b * NPT + c0 + cg * 4);
    __syncthreads();  // all colB dot-reads done before overwriting with scores

    // write scores swizzled: col' = ((cg ^ (row&31))<<2) | (c ^ ((row>>3)&3))
#pragma unroll
    for (int i = 0; i < 8; ++i) {
      const int row = rg * 8 + i;
      float* sr = &colB[row * 128];
      const int cgx = ((cg ^ (row & 31)) << 2);
      const int q3  = (row >> 3) & 3;
      sr[cgx | (0 ^ q3)] = fmaf(-2.f, acc[i][0], sqv.x);
      sr[cgx | (1 ^ q3)] = fmaf(-2.f, acc[i][1], sqv.y);
      sr[cgx | (2 ^ q3)] = fmaf(-2.f, acc[i][2], sqv.z);
      sr[cgx | (3 ^ q3)] = fmaf(-2.f, acc[i][3], sqv.w);
    }
    __syncthreads();

    // selection: thread (selrow, selseg) scans 32 cols, branchless insert
    {
      const float* sr = &colB[selrow * 128];
#pragma unroll
      for (int j = 0; j < 32; ++j) {
        const int col = selseg * 32 + j;
        const int sw = (((col >> 2) ^ srb5) << 2) | ((col & 3) ^ sq3);
        ins(sr[sw], c0 + col);
      }
    }
  }

  // publish per-(row,seg) sorted top-8
  {
    float* cd = &cand_d[selrow][selseg * 8];
    int*   ci = &cand_i[selrow][selseg * 8];
    cd[0]=d0; cd[1]=d1; cd[2]=d2; cd[3]=d3; cd[4]=d4; cd[5]=d5; cd[6]=d6; cd[7]=d7;
    ci[0]=i0; ci[1]=i1; ci[2]=i2; ci[3]=i3; ci[4]=i4; ci[5]=i5; ci[6]=i6; ci[7]=i7;
  }
  __syncthreads();

  // 4-way sorted-list head merge per row (named heads, low-index tie-break)
  if (tid < 64) {
    const int r = tid;
    int h0=0,h1=0,h2=0,h3=0;
    int* outp = nbr + ((size_t)b * NPT + r0 + r) * KNN;
#pragma unroll 1
    for (int s = 0; s < 8; ++s) {
      float bd = cand_d[r][h0]; int bi = cand_i[r][h0]; int bw = 0;
      { const float cd_=cand_d[r][ 8+h1]; const int ci_=cand_i[r][ 8+h1];
        if (cd_<bd || (cd_==bd && ci_<bi)) { bd=cd_; bi=ci_; bw=1; } }
      { const float cd_=cand_d[r][16+h2]; const int ci_=cand_i[r][16+h2];
        if (cd_<bd || (cd_==bd && ci_<bi)) { bd=cd_; bi=ci_; bw=2; } }
      { const float cd_=cand_d[r][24+h3]; const int ci_=cand_i[r][24+h3];
        if (cd_<bd || (cd_==bd && ci_<bi)) { bd=cd_; bi=ci_; bw=3; } }
      outp[s] = bi;
      h0 += (bw==0); h1 += (bw==1); h2 += (bw==2); h3 += (bw==3);
    }
  }
}

// ---------------- kernel 3: gather + fused dual matvec ----------------
__global__ __launch_bounds__(256, 2) void k_out(const float* __restrict__ xt,
                                                const int* __restrict__ nbr,
                                                const float* __restrict__ Wd,
                                                const float* __restrict__ bdv,
                                                const float* __restrict__ Ws,
                                                const float* __restrict__ bsv,
                                                const float* __restrict__ bias,
                                                float* __restrict__ out) {
  __shared__ float wtd[64][68];
  __shared__ float wts[64][68];
  __shared__ float mdt[64][65];
  __shared__ float xrt[64][65];
  __shared__ float cb[64];

  const int bid = blockIdx.x;
  const int b   = bid >> 4;
  const int r0  = (bid & 15) << 6;
  const int tid = threadIdx.x;

  {
    const int fl = tid & 63, og = tid >> 6;
#pragma unroll
    for (int i = 0; i < 16; ++i) {
      const int o = og * 16 + i;
      wtd[fl][o] = Wd[o * 64 + fl];
      wts[fl][o] = Ws[o * 64 + fl];
    }
    if (tid < 64) cb[tid] = bdv[tid] + bsv[tid] + bias[tid];
  }

  {
    const int r = tid & 63, c = tid >> 6;
    const int row = r0 + r;
    const int* np = nbr + ((size_t)b * NPT + row) * KNN;
    float s[16];
#pragma unroll
    for (int q = 0; q < 16; ++q) s[q] = 0.f;
    for (int s8 = 0; s8 < 8; ++s8) {
      const int j = np[s8];
      const float4* nv = (const float4*)(xt + ((size_t)b * NPT + j) * FDIM + c * 16);
#pragma unroll
      for (int q = 0; q < 4; ++q) {
        const float4 v = nv[q];
        s[q * 4 + 0] += v.x; s[q * 4 + 1] += v.y;
        s[q * 4 + 2] += v.z; s[q * 4 + 3] += v.w;
      }
    }
    const float4* xv4 = (const float4*)(xt + ((size_t)b * NPT + row) * FDIM + c * 16);
#pragma unroll
    for (int q = 0; q < 4; ++q) {
      const float4 xv = xv4[q];
      const int f = c * 16 + q * 4;
      mdt[f + 0][r] = fmaf(s[q * 4 + 0], 0.125f, -xv.x);
      mdt[f + 1][r] = fmaf(s[q * 4 + 1], 0.125f, -xv.y);
      mdt[f + 2][r] = fmaf(s[q * 4 + 2], 0.125f, -xv.z);
      mdt[f + 3][r] = fmaf(s[q * 4 + 3], 0.125f, -xv.w);
      xrt[f + 0][r] = xv.x;
      xrt[f + 1][r] = xv.y;
      xrt[f + 2][r] = xv.z;
      xrt[f + 3][r] = xv.w;
    }
  }
  __syncthreads();

  {
    const int r = tid & 63, oc = tid >> 6;
    float acc[16];
#pragma unroll
    for (int j = 0; j < 16; ++j) acc[j] = cb[oc * 16 + j];
#pragma unroll 4
    for (int f = 0; f < 64; ++f) {
      const float mv = mdt[f][r];
      const float xv = xrt[f][r];
      const float4* w4 = (const float4*)(&wtd[f][oc * 16]);
      const float4* v4 = (const float4*)(&wts[f][oc * 16]);
#pragma unroll
      for (int q = 0; q < 4; ++q) {
        const float4 a = w4[q], bb = v4[q];
        acc[q * 4 + 0] = fmaf(a.x, mv, fmaf(bb.x, xv, acc[q * 4 + 0]));
        acc[q * 4 + 1] = fmaf(a.y, mv, fmaf(bb.y, xv, acc[q * 4 + 1]));
        acc[q * 4 + 2] = fmaf(a.z, mv, fmaf(bb.z, xv, acc[q * 4 + 2]));
        acc[q * 4 + 3] = fmaf(a.w, mv, fmaf(bb.w, xv, acc[q * 4 + 3]));
      }
    }
    const int row = r0 + r;
    float* op = out + (size_t)b * OCH * NPT + row;
#pragma unroll
    for (int j = 0; j < 16; ++j) op[(oc * 16 + j) * NPT] = acc[j];
  }
}

extern "C" void kernel_launch(void* const* d_in, const int* in_sizes, int n_in,
                              void* d_out, int out_size, void* d_ws, size_t ws_size,
                              hipStream_t stream) {
  const float* x    = (const float*)d_in[0];
  const float* Wd   = (const float*)d_in[1];
  const float* bd   = (const float*)d_in[2];
  const float* Ws   = (const float*)d_in[3];
  const float* bs   = (const float*)d_in[4];
  const float* bias = (const float*)d_in[5];
  float* out = (float*)d_out;

  float* xt  = (float*)d_ws;                          // 2,097,152 floats
  float* sqw = xt + (size_t)BATCH * NPT * FDIM;       //    32,768 floats
  int*   nbr = (int*)(sqw + (size_t)BATCH * NPT);     //   262,144 ints

  k_prep<<<dim3(BATCH * 16), dim3(256), 0, stream>>>(x, xt, sqw);
  k_knn <<<dim3(BATCH * 16), dim3(256), 0, stream>>>(x, sqw, nbr);
  k_out <<<dim3(BATCH * 16), dim3(256), 0, stream>>>(xt, nbr, Wd, bd, Ws, bs, bias, out);
}

// Round 9
// 188.343 us; speedup vs baseline: 2.7487x; 1.0291x over previous
//
#include <hip/hip_runtime.h>

// NonLocalAggregation on MI355X.
// Sizes fixed by setup_inputs(): b=32, f=64, h=w=32 (n=1024), out=64, k=8.
// Workspace: xt [32][1024][64] fp32, sq [32][1024] fp32, nbr [32][1024][8] int.
#define BATCH 32
#define FDIM  64
#define NPT   1024
#define KNN   8
#define OCH   64
#define INFF  3.402823466e+38f

// ---------------- kernel 1: transpose + squared norms ----------------
__global__ __launch_bounds__(256) void k_prep(const float* __restrict__ x,
                                              float* __restrict__ xt,
                                              float* __restrict__ sq) {
  __shared__ float t[64][65];
  const int bid = blockIdx.x;
  const int b   = bid >> 4;
  const int n0  = (bid & 15) << 6;
  const int tid = threadIdx.x;
  const int nl  = tid & 63;
  const int f0  = tid >> 6;
  const float* xb = x + (size_t)b * FDIM * NPT;
#pragma unroll
  for (int i = 0; i < 16; ++i) {
    const int f = f0 * 16 + i;
    t[f][nl] = xb[f * NPT + n0 + nl];
  }
  __syncthreads();
  const int fl = tid & 63;
  const int g0 = tid >> 6;
  float* xtb = xt + ((size_t)b * NPT + n0) * FDIM;
#pragma unroll
  for (int i = 0; i < 16; ++i) {
    const int nn = g0 * 16 + i;
    xtb[nn * FDIM + fl] = t[fl][nn];
  }
  if (tid < 64) {
    float s = 0.f;
#pragma unroll
    for (int f = 0; f < 64; ++f) s = fmaf(t[f][tid], t[f][tid], s);
    sq[b * NPT + n0 + tid] = s;
  }
}

// ---------------- kernel 2: pairwise distances + top-8 (v4) ----------------
// Round-7 lesson: scalar b32 score writes at 16B stride hit only 8/32 banks
// (8-way conflict, 3.22M counter) — a quad-index XOR cannot change the bank
// SET of a single instruction. v4: float4 score write at quad (cg^row)&31
// (64 lanes -> 64 distinct quads, conflict-free) and float4 selection reads
// of logical quad q at physical (q^selrow)&31 (32 quads x2 -> free 2-way).
// LDS diet: colB stride 128 (dot reads are f-uniform; pad unneeded), cand
// arrays folded into colB after last selection -> 49.4 KB -> 3 blocks/CU.
__global__ __launch_bounds__(256, 2) void k_knn(const float* __restrict__ x,
                                                const float* __restrict__ sq,
                                                int* __restrict__ nbr) {
  __shared__ float rowF[64][68];     // [f][row-local]
  __shared__ float colB[64 * 128];   // staging [f][col] / scores [row][quad swz] / cand publish

  const int bid = blockIdx.x;
  const int b   = bid >> 4;          // 512 blocks: 32 batches x 16 row-tiles
  const int r0  = (bid & 15) << 6;
  const int tid = threadIdx.x;
  const int rg  = tid >> 5;          // row group 0..7 (8 rows each)
  const int cg  = tid & 31;          // col quad 0..31 (4 cols each)

  const float* xb = x + (size_t)b * FDIM * NPT;

  // stage rowF once: rows r0..r0+63, all 64 features (coalesced)
#pragma unroll
  for (int k = 0; k < 4; ++k) {
    const int qid = tid + k * 256;
    const int f = qid >> 4, rq = qid & 15;
    *(float4*)(&rowF[f][rq * 4]) = *(const float4*)(xb + f * NPT + r0 + rq * 4);
  }

  // ascending sorted top-8 in NAMED regs, branchless insert (proven r5/r7)
  float d0=INFF,d1=INFF,d2=INFF,d3=INFF,d4=INFF,d5=INFF,d6=INFF,d7=INFF;
  int   i0=0,i1=0,i2=0,i3=0,i4=0,i5=0,i6=0,i7=0;
  auto ins = [&](float k, int idx) {
    const bool c0 = k < d0, c1 = k < d1, c2 = k < d2, c3 = k < d3,
               c4 = k < d4, c5 = k < d5, c6 = k < d6, c7 = k < d7;
    d7 = c6 ? d6 : (c7 ? k : d7);  i7 = c6 ? i6 : (c7 ? idx : i7);
    d6 = c5 ? d5 : (c6 ? k : d6);  i6 = c5 ? i5 : (c6 ? idx : i6);
    d5 = c4 ? d4 : (c5 ? k : d5);  i5 = c4 ? i4 : (c5 ? idx : i5);
    d4 = c3 ? d3 : (c4 ? k : d4);  i4 = c3 ? i3 : (c4 ? idx : i4);
    d3 = c2 ? d2 : (c3 ? k : d3);  i3 = c2 ? i2 : (c3 ? idx : i3);
    d2 = c1 ? d1 : (c2 ? k : d2);  i2 = c1 ? i1 : (c2 ? idx : i2);
    d1 = c0 ? d0 : (c1 ? k : d1);  i1 = c0 ? i0 : (c1 ? idx : i1);
    d0 = c0 ? k  : d0;             i0 = c0 ? idx : i0;
  };

  const int selrow = tid & 63;       // selection: 64 rows x 4 col-segments
  const int selseg = tid >> 6;       // wave-uniform
  const int srb5   = selrow & 31;

  for (int ct = 0; ct < 8; ++ct) {
    const int c0 = ct * 128;
    __syncthreads();  // prev selection reads done -> colB writable
    // stage colF[f][c], stride 128 (all later reads are f-uniform)
#pragma unroll
    for (int k = 0; k < 8; ++k) {
      const int qid = tid + k * 256;
      const int f = qid >> 5, cq = qid & 31;
      *(float4*)(&colB[f * 128 + cq * 4]) = *(const float4*)(xb + f * NPT + c0 + cq * 4);
    }
    __syncthreads();

    float acc[8][4];
#pragma unroll
    for (int i = 0; i < 8; ++i)
#pragma unroll
      for (int c = 0; c < 4; ++c) acc[i][c] = 0.f;

#pragma unroll 4
    for (int f = 0; f < 64; ++f) {
      const float4 ra = *(const float4*)(&rowF[f][rg * 8]);      // broadcast
      const float4 rb = *(const float4*)(&rowF[f][rg * 8 + 4]);
      const float4 cv = *(const float4*)(&colB[f * 128 + cg * 4]);
      const float rv[8]  = {ra.x, ra.y, ra.z, ra.w, rb.x, rb.y, rb.z, rb.w};
      const float cvv[4] = {cv.x, cv.y, cv.z, cv.w};
#pragma unroll
      for (int i = 0; i < 8; ++i)
#pragma unroll
        for (int c = 0; c < 4; ++c)
          acc[i][c] = fmaf(rv[i], cvv[c], acc[i][c]);
    }

    // score = sq[col] - 2*dot (row-constant term dropped: ordering invariant)
    const float4 sqv = *(const float4*)(sq + (size_t)b * NPT + c0 + cg * 4);
    __syncthreads();  // all dot reads of colB done before overwrite

    // ONE float4 per (thread,row): logical quad cg stored at physical quad
    // cg^(row&31). 64 lanes -> 64 distinct quads -> conflict-free.
#pragma unroll
    for (int i = 0; i < 8; ++i) {
      const int row = rg * 8 + i;
      float4 v;
      v.x = fmaf(-2.f, acc[i][0], sqv.x);
      v.y = fmaf(-2.f, acc[i][1], sqv.y);
      v.z = fmaf(-2.f, acc[i][2], sqv.z);
      v.w = fmaf(-2.f, acc[i][3], sqv.w);
      *(float4*)(&colB[row * 128 + ((cg ^ (row & 31)) << 2)]) = v;
    }
    __syncthreads();

    // selection: thread (selrow,selseg) reads 8 logical quads as float4
    {
      const float* srp = &colB[selrow * 128];
#pragma unroll
      for (int jq = 0; jq < 8; ++jq) {
        const int lq = selseg * 8 + jq;                       // logical quad
        const float4 sv = *(const float4*)(&srp[(lq ^ srb5) << 2]);
        const int base = c0 + lq * 4;
        ins(sv.x, base);     ins(sv.y, base + 1);
        ins(sv.z, base + 2); ins(sv.w, base + 3);
      }
    }
  }

  // publish per-(row,seg) sorted top-8 into colB (free after last selection)
  __syncthreads();
  {
    float* cdp = (float*)colB;                 // [64][33]
    int*   cip = (int*)(colB + 64 * 33);       // [64][33]
    float* cd = &cdp[selrow * 33 + selseg * 8];
    int*   ci = &cip[selrow * 33 + selseg * 8];
    cd[0]=d0; cd[1]=d1; cd[2]=d2; cd[3]=d3; cd[4]=d4; cd[5]=d5; cd[6]=d6; cd[7]=d7;
    ci[0]=i0; ci[1]=i1; ci[2]=i2; ci[3]=i3; ci[4]=i4; ci[5]=i5; ci[6]=i6; ci[7]=i7;
  }
  __syncthreads();

  // 4-way sorted-list head merge per row (named heads, low-index tie-break)
  if (tid < 64) {
    const float* cd = (const float*)colB + tid * 33;
    const int*   ci = (const int*)(colB + 64 * 33) + tid * 33;
    int h0=0,h1=0,h2=0,h3=0;
    int* outp = nbr + ((size_t)b * NPT + r0 + tid) * KNN;
#pragma unroll 1
    for (int s = 0; s < 8; ++s) {
      float bd = cd[h0]; int bi = ci[h0]; int bw = 0;
      { const float cd_=cd[ 8+h1]; const int ci_=ci[ 8+h1];
        if (cd_<bd || (cd_==bd && ci_<bi)) { bd=cd_; bi=ci_; bw=1; } }
      { const float cd_=cd[16+h2]; const int ci_=ci[16+h2];
        if (cd_<bd || (cd_==bd && ci_<bi)) { bd=cd_; bi=ci_; bw=2; } }
      { const float cd_=cd[24+h3]; const int ci_=ci[24+h3];
        if (cd_<bd || (cd_==bd && ci_<bi)) { bd=cd_; bi=ci_; bw=3; } }
      outp[s] = bi;
      h0 += (bw==0); h1 += (bw==1); h2 += (bw==2); h3 += (bw==3);
    }
  }
}

// ---------------- kernel 3: gather + fused dual matvec ----------------
__global__ __launch_bounds__(256, 2) void k_out(const float* __restrict__ xt,
                                                const int* __restrict__ nbr,
                                                const float* __restrict__ Wd,
                                                const float* __restrict__ bdv,
                                                const float* __restrict__ Ws,
                                                const float* __restrict__ bsv,
                                                const float* __restrict__ bias,
                                                float* __restrict__ out) {
  __shared__ float wtd[64][68];
  __shared__ float wts[64][68];
  __shared__ float mdt[64][65];
  __shared__ float xrt[64][65];
  __shared__ float cb[64];

  const int bid = blockIdx.x;
  const int b   = bid >> 4;
  const int r0  = (bid & 15) << 6;
  const int tid = threadIdx.x;

  {
    const int fl = tid & 63, og = tid >> 6;
#pragma unroll
    for (int i = 0; i < 16; ++i) {
      const int o = og * 16 + i;
      wtd[fl][o] = Wd[o * 64 + fl];
      wts[fl][o] = Ws[o * 64 + fl];
    }
    if (tid < 64) cb[tid] = bdv[tid] + bsv[tid] + bias[tid];
  }

  {
    const int r = tid & 63, c = tid >> 6;
    const int row = r0 + r;
    const int* np = nbr + ((size_t)b * NPT + row) * KNN;
    float s[16];
#pragma unroll
    for (int q = 0; q < 16; ++q) s[q] = 0.f;
    for (int s8 = 0; s8 < 8; ++s8) {
      const int j = np[s8];
      const float4* nv = (const float4*)(xt + ((size_t)b * NPT + j) * FDIM + c * 16);
#pragma unroll
      for (int q = 0; q < 4; ++q) {
        const float4 v = nv[q];
        s[q * 4 + 0] += v.x; s[q * 4 + 1] += v.y;
        s[q * 4 + 2] += v.z; s[q * 4 + 3] += v.w;
      }
    }
    const float4* xv4 = (const float4*)(xt + ((size_t)b * NPT + row) * FDIM + c * 16);
#pragma unroll
    for (int q = 0; q < 4; ++q) {
      const float4 xv = xv4[q];
      const int f = c * 16 + q * 4;
      mdt[f + 0][r] = fmaf(s[q * 4 + 0], 0.125f, -xv.x);
      mdt[f + 1][r] = fmaf(s[q * 4 + 1], 0.125f, -xv.y);
      mdt[f + 2][r] = fmaf(s[q * 4 + 2], 0.125f, -xv.z);
      mdt[f + 3][r] = fmaf(s[q * 4 + 3], 0.125f, -xv.w);
      xrt[f + 0][r] = xv.x;
      xrt[f + 1][r] = xv.y;
      xrt[f + 2][r] = xv.z;
      xrt[f + 3][r] = xv.w;
    }
  }
  __syncthreads();

  {
    const int r = tid & 63, oc = tid >> 6;
    float acc[16];
#pragma unroll
    for (int j = 0; j < 16; ++j) acc[j] = cb[oc * 16 + j];
#pragma unroll 4
    for (int f = 0; f < 64; ++f) {
      const float mv = mdt[f][r];
      const float xv = xrt[f][r];
      const float4* w4 = (const float4*)(&wtd[f][oc * 16]);
      const float4* v4 = (const float4*)(&wts[f][oc * 16]);
#pragma unroll
      for (int q = 0; q < 4; ++q) {
        const float4 a = w4[q], bb = v4[q];
        acc[q * 4 + 0] = fmaf(a.x, mv, fmaf(bb.x, xv, acc[q * 4 + 0]));
        acc[q * 4 + 1] = fmaf(a.y, mv, fmaf(bb.y, xv, acc[q * 4 + 1]));
        acc[q * 4 + 2] = fmaf(a.z, mv, fmaf(bb.z, xv, acc[q * 4 + 2]));
        acc[q * 4 + 3] = fmaf(a.w, mv, fmaf(bb.w, xv, acc[q * 4 + 3]));
      }
    }
    const int row = r0 + r;
    float* op = out + (size_t)b * OCH * NPT + row;
#pragma unroll
    for (int j = 0; j < 16; ++j) op[(oc * 16 + j) * NPT] = acc[j];
  }
}

extern "C" void kernel_launch(void* const* d_in, const int* in_sizes, int n_in,
                              void* d_out, int out_size, void* d_ws, size_t ws_size,
                              hipStream_t stream) {
  const float* x    = (const float*)d_in[0];
  const float* Wd   = (const float*)d_in[1];
  const float* bd   = (const float*)d_in[2];
  const float* Ws   = (const float*)d_in[3];
  const float* bs   = (const float*)d_in[4];
  const float* bias = (const float*)d_in[5];
  float* out = (float*)d_out;

  float* xt  = (float*)d_ws;                          // 2,097,152 floats
  float* sqw = xt + (size_t)BATCH * NPT * FDIM;       //    32,768 floats
  int*   nbr = (int*)(sqw + (size_t)BATCH * NPT);     //   262,144 ints

  k_prep<<<dim3(BATCH * 16), dim3(256), 0, stream>>>(x, xt, sqw);
  k_knn <<<dim3(BATCH * 16), dim3(256), 0, stream>>>(x, sqw, nbr);
  k_out <<<dim3(BATCH * 16), dim3(256), 0, stream>>>(xt, nbr, Wd, bd, Ws, bs, bias, out);
}